// Round 3
// baseline (474326.514 us; speedup 1.0000x reference)
//
#include <hip/hip_runtime.h>
#include <math.h>

// ---------------- problem constants ----------------
#define TBATCH 32
#define TMEM   200
#define TSTEPS 400
#define DENC   512
#define DL     1024
#define G4     4096   // 4*DL
#define DATT   128
#define DPRE   256
#define NMEL   80
#define K1     1792   // 256 (x) + 512 (ctx) + 1024 (h1)
#define KSPL1  768    // rows in lstm1_k
#define KC1    112    // K1/16
#define K2     2560   // 1024 (h1) + 512 (ctx) + 1024 (h2)
#define KSPL2  1536   // rows in lstm2_k
#define KC2    160    // K2/16

#define NBLK 256
#define NTHR 1024

// ---------------- workspace layout (float offsets) ----------------
#define OFF_XPRE  0u
#define SZ_XPRE   (400u*32u*256u)            // prenet outputs [t][b][256]
#define OFF_PM    (OFF_XPRE + SZ_XPRE)
#define SZ_PM     (32u*200u*128u)            // tanh(memory@wm) [b][t][128]
#define OFF_IN1T  (OFF_PM + SZ_PM)
#define SZ_IN1T   (1792u*32u)                // lstm1 input, transposed [k][b]
#define OFF_IN2T  (OFF_IN1T + SZ_IN1T)
#define SZ_IN2T   (2560u*32u)                // lstm2 input, transposed [k][b]
#define OFF_ZP    (OFF_IN2T + SZ_IN2T)
#define SZ_ZP     (16u*32u*4096u)            // gate partials [kc][b][4096]
#define OFF_C1    (OFF_ZP + SZ_ZP)           // c1 [b][1024]
#define OFF_C2    (OFF_C1 + 32768u)          // c2
#define OFF_CTX   (OFF_C2 + 32768u)          // ctx [b][512]
#define OFF_ATTW  (OFF_CTX + 16384u)         // att_w [b][200]
#define OFF_CUM   (OFF_ATTW + 6400u)         // att_w_cum
#define OFF_EEXP  (OFF_CUM + 6400u)          // exp(energies)
#define OFF_Q     (OFF_EEXP + 6400u)         // q [b][128]
#define OFF_DENP  (OFF_Q + 4096u)            // softmax denom partials [b][8]
#define OFF_BAR   (OFF_DENP + 256u)          // barrier: 256 flags x 32 words + gen line
#define SZ_BAR    (256u*32u + 32u)
#define WS_FLOATS (OFF_BAR + SZ_BAR)

// output layout (floats)
#define OUT_GATE  1024000   // 32*80*400
#define OUT_ALIGN 1036800   // + 32*400

__device__ __forceinline__ float sigf(float x)   { return 1.f / (1.f + __expf(-x)); }
__device__ __forceinline__ float tanhf_(float x) { return 1.f - 2.f / (__expf(2.f*x) + 1.f); }

// ---------------- distributed-arrival grid barrier ----------------
// Each block release-stores generation n into its OWN 128B-padded flag
// (no RMW, no line sharing). Block 0's threads 0..255 poll the 256 flags in
// parallel, then one release store to gen; everyone else polls gen (read-only
// line). Avoids the 256-serialized-RMW contention of a single atomic counter.
__device__ __forceinline__ void grid_barrier(unsigned* flags, unsigned* gen, unsigned n) {
    __syncthreads();
    if (threadIdx.x == 0) {
        __threadfence();
        __hip_atomic_store(flags + blockIdx.x * 32, n, __ATOMIC_RELEASE, __HIP_MEMORY_SCOPE_AGENT);
    }
    if (blockIdx.x == 0) {
        if (threadIdx.x < NBLK) {
            while (__hip_atomic_load(flags + threadIdx.x * 32, __ATOMIC_ACQUIRE, __HIP_MEMORY_SCOPE_AGENT) < n)
                __builtin_amdgcn_s_sleep(1);
        }
        __syncthreads();
        if (threadIdx.x == 0)
            __hip_atomic_store(gen, n, __ATOMIC_RELEASE, __HIP_MEMORY_SCOPE_AGENT);
    } else {
        if (threadIdx.x == 0) {
            while (__hip_atomic_load(gen, __ATOMIC_ACQUIRE, __HIP_MEMORY_SCOPE_AGENT) < n)
                __builtin_amdgcn_s_sleep(1);
        }
    }
    __threadfence();
    __syncthreads();
}

// ---------------- P1: prenet for all 400 frames (+ zero barrier area) ----------------
__global__ void __launch_bounds__(256) prenet_kernel(
    const float* __restrict__ dec, const float* __restrict__ w0, const float* __restrict__ b0,
    const float* __restrict__ w1, const float* __restrict__ b1, float* __restrict__ ws)
{
    __shared__ float s_in[80];
    __shared__ float s_h0[256];
    int t = blockIdx.x, b = blockIdx.y, tid = threadIdx.x;
    if (tid < 80) s_in[tid] = (t == 0) ? 0.f : dec[b*32000 + tid*400 + (t-1)];
    if (blockIdx.x == 0 && blockIdx.y == 0) {
        unsigned* bw = (unsigned*)(ws + OFF_BAR);
        for (int i = tid; i < (int)SZ_BAR; i += 256) bw[i] = 0u;
    }
    __syncthreads();
    float s = b0[tid];
    for (int m = 0; m < 80; ++m) s = fmaf(s_in[m], w0[m*256 + tid], s);
    s_h0[tid] = fmaxf(s, 0.f);
    __syncthreads();
    float s2 = b1[tid];
    for (int k = 0; k < 256; ++k) s2 = fmaf(s_h0[k], w1[k*256 + tid], s2);
    ws[OFF_XPRE + (t*32 + b)*256 + tid] = fmaxf(s2, 0.f);
}

// ---------------- P2: processed_memory = tanh(memory @ wm) ----------------
__global__ void __launch_bounds__(128) pmem_kernel(
    const float* __restrict__ mp, const float* __restrict__ wm, float* __restrict__ ws)
{
    int t = blockIdx.x, b = blockIdx.y, a = threadIdx.x;
    const float* mrow = mp + (b*200 + t)*512;
    float s = 0.f;
    for (int d = 0; d < 512; ++d) s = fmaf(mrow[d], wm[d*128 + a], s);
    ws[OFF_PM + (b*200 + t)*128 + a] = tanhf_(s);
}

// ---------------- GEMV partial ----------------
// 256 blocks = 16 jb x 16 kc. 1024 threads = 16 bgrp(x2 batch) x 64 jgrp(x4 cols).
// Per k: 1 float4 weight load (coalesced 1KB/wave) + 1 float2 input broadcast
// (wave-uniform address -> 1 transaction), 8 FMAs. unroll 8 -> 8 weight loads
// in flight per wave -> kcsize/8 sequential latency batches.
__device__ __forceinline__ void gemv_block(
    const float* __restrict__ Wk, const float* __restrict__ Wr, int ksplit,
    const float* __restrict__ inT, float* __restrict__ zp, int kcsize)
{
    const int jb = blockIdx.x >> 4, kc = blockIdx.x & 15;
    const int jgrp = threadIdx.x & 63;
    const int bgrp = threadIdx.x >> 6;
    const int j = (jb << 8) + (jgrp << 2);
    const int b0 = bgrp << 1;
    float4 a0 = {0.f,0.f,0.f,0.f}, a1 = {0.f,0.f,0.f,0.f};
    const int k0 = kc * kcsize, k1 = k0 + kcsize;
    const int ka = min(k1, ksplit);
#pragma unroll 8
    for (int k = k0; k < ka; ++k) {
        float4 w = *(const float4*)(Wk + k*4096 + j);
        float2 x = *(const float2*)(inT + k*32 + b0);
        a0.x = fmaf(x.x, w.x, a0.x); a0.y = fmaf(x.x, w.y, a0.y);
        a0.z = fmaf(x.x, w.z, a0.z); a0.w = fmaf(x.x, w.w, a0.w);
        a1.x = fmaf(x.y, w.x, a1.x); a1.y = fmaf(x.y, w.y, a1.y);
        a1.z = fmaf(x.y, w.z, a1.z); a1.w = fmaf(x.y, w.w, a1.w);
    }
    const int kb = max(k0, ksplit);
#pragma unroll 8
    for (int k = kb; k < k1; ++k) {
        float4 w = *(const float4*)(Wr + (k - ksplit)*4096 + j);
        float2 x = *(const float2*)(inT + k*32 + b0);
        a0.x = fmaf(x.x, w.x, a0.x); a0.y = fmaf(x.x, w.y, a0.y);
        a0.z = fmaf(x.x, w.z, a0.z); a0.w = fmaf(x.x, w.w, a0.w);
        a1.x = fmaf(x.y, w.x, a1.x); a1.y = fmaf(x.y, w.y, a1.y);
        a1.z = fmaf(x.y, w.z, a1.z); a1.w = fmaf(x.y, w.w, a1.w);
    }
    float* zr = zp + (kc*32 + b0)*4096 + j;
    *(float4*)zr = a0;
    *(float4*)(zr + 4096) = a1;
}

// ---------------- persistent decoder loop ----------------
__global__ void __launch_bounds__(NTHR, 4) decoder_loop(
    const float* __restrict__ mp,
    const float* __restrict__ l1k, const float* __restrict__ l1r, const float* __restrict__ l1b,
    const float* __restrict__ l2k, const float* __restrict__ l2r, const float* __restrict__ l2b,
    const float* __restrict__ wq, const float* __restrict__ vvec,
    const float* __restrict__ lconv, const float* __restrict__ ldense,
    const float* __restrict__ fw, const float* __restrict__ fb,
    const float* __restrict__ sw, const float* __restrict__ sb,
    float* __restrict__ ws, float* __restrict__ out)
{
    __shared__ float s_convw[31*2*32];
    __shared__ float s_ldense[32*128];
    __shared__ float s_v[128];
    __shared__ float s_wwin[56], s_cwin[56];
    __shared__ float s_co[25*33];
    __shared__ float s_ea[25*128];
    __shared__ float s_q[128];
    __shared__ float s_ex[32];
    __shared__ float s_hid[1024];
    __shared__ float s_red[1024];

    float* xpre = ws + OFF_XPRE;
    float* pm   = ws + OFF_PM;
    float* in1T = ws + OFF_IN1T;
    float* in2T = ws + OFF_IN2T;
    float* zp   = ws + OFF_ZP;
    float* c1a  = ws + OFF_C1;
    float* c2a  = ws + OFF_C2;
    float* ctx  = ws + OFF_CTX;
    float* attw = ws + OFF_ATTW;
    float* cum  = ws + OFF_CUM;
    float* eexp = ws + OFF_EEXP;
    float* qarr = ws + OFF_Q;
    float* denp = ws + OFF_DENP;
    unsigned* flags = (unsigned*)(ws + OFF_BAR);
    unsigned* gen   = flags + 256*32;
    unsigned bnum = 0;

    const int tid = threadIdx.x;
    const int gid = blockIdx.x * NTHR + tid;
    const int gsz = NBLK * NTHR;

    // persistent LDS fill
    for (int i = tid; i < 1984; i += NTHR) s_convw[i] = lconv[i];
    for (int i = tid; i < 4096; i += NTHR) s_ldense[i] = ldense[i];
    if (tid < 128) s_v[tid] = vvec[tid];

    // ---- init (ws is poisoned before every call) ----
    for (int i = gid; i < (int)SZ_IN1T - 256*32; i += gsz) in1T[256*32 + i] = 0.f;
    for (int i = gid; i < (int)SZ_IN2T; i += gsz) in2T[i] = 0.f;
    for (int i = gid; i < 32768; i += gsz) { c1a[i] = 0.f; c2a[i] = 0.f; }
    for (int i = gid; i < 6400;  i += gsz) { attw[i] = 0.f; cum[i] = 0.f; }
    for (int i = gid; i < 8192;  i += gsz) {
        int k = i >> 5, b = i & 31;
        in1T[i] = xpre[b*256 + k];
    }
    grid_barrier(flags, gen, ++bnum);

#pragma unroll 1
    for (int t = 0; t < TSTEPS; ++t) {
        // ---- S1: LSTM1 gate partials ----
        gemv_block(l1k, l1r, KSPL1, in1T, zp, KC1);
        grid_barrier(flags, gen, ++bnum);

        // ---- S2: reduce -> gates -> h1,c1 ; q = tanh(h1@wq) ----
        if (blockIdx.x < 32) {
            int b = blockIdx.x;
            {
                int u = tid;
                float zi = l1b[u], zf = l1b[1024+u], zg = l1b[2048+u], zo = l1b[3072+u];
#pragma unroll 8
                for (int kc = 0; kc < 16; ++kc) {
                    const float* zr = zp + (kc*32 + b)*4096;
                    zi += zr[u]; zf += zr[1024+u]; zg += zr[2048+u]; zo += zr[3072+u];
                }
                float c = sigf(zf)*c1a[b*1024+u] + sigf(zi)*tanhf_(zg);
                float h = sigf(zo)*tanhf_(c);
                c1a[b*1024+u] = c;
                in1T[(768+u)*32 + b] = h;
                in2T[u*32 + b] = h;
                s_hid[u] = h;
            }
            __syncthreads();
            {
                int a = tid & 127, kq = tid >> 7;   // 8 k-chunks of 128
                float s = 0.f;
                for (int k = kq*128; k < kq*128 + 128; ++k)
                    s = fmaf(s_hid[k], wq[k*128 + a], s);
                s_red[tid] = s;
            }
            __syncthreads();
            if (tid < 128) {
                float s = 0.f;
#pragma unroll
                for (int q = 0; q < 8; ++q) s += s_red[q*128 + tid];
                qarr[b*128 + tid] = tanhf_(s);
            }
        }
        grid_barrier(flags, gen, ++bnum);

        // ---- S3: location attention -> exp(energies), per-chunk denom partial ----
        {
            int b = blockIdx.x >> 3, tc = blockIdx.x & 7;
            int t0 = tc * 25;
            if (tid < 56)      { int tg = t0 - 15 + tid; s_wwin[tid] = (tg >= 0 && tg < 200) ? attw[b*200 + tg] : 0.f; }
            else if (tid < 112){ int i = tid - 56; int tg = t0 - 15 + i; s_cwin[i] = (tg >= 0 && tg < 200) ? cum[b*200 + tg] : 0.f; }
            else if (tid >= 112 && tid < 240) { int a = tid - 112; if (a < 128) s_q[a] = qarr[b*128 + a]; }
            __syncthreads();
            for (int idx = tid; idx < 800; idx += NTHR) {
                int tl = idx >> 5, f = idx & 31;
                float s = 0.f;
                for (int dw = 0; dw < 31; ++dw) {
                    s = fmaf(s_wwin[tl + dw], s_convw[(dw*2+0)*32 + f], s);
                    s = fmaf(s_cwin[tl + dw], s_convw[(dw*2+1)*32 + f], s);
                }
                s_co[tl*33 + f] = s;
            }
            __syncthreads();
            for (int idx = tid; idx < 3200; idx += NTHR) {
                int tl = idx >> 7, a = idx & 127;
                float s = 0.f;
#pragma unroll
                for (int f = 0; f < 32; ++f) s = fmaf(s_co[tl*33 + f], s_ldense[f*128 + a], s);
                float loc = tanhf_(s);
                float en = tanhf_(s_q[a] + loc + pm[(b*200 + t0 + tl)*128 + a]);
                s_ea[idx] = en * s_v[a];
            }
            __syncthreads();
            if (tid < 200) {
                int tl = tid >> 3, ln = tid & 7;
                float s = 0.f;
                for (int a = ln; a < 128; a += 8) s += s_ea[tl*128 + a];
                s += __shfl_down(s, 4, 8);
                s += __shfl_down(s, 2, 8);
                s += __shfl_down(s, 1, 8);
                if (ln == 0) {
                    float ex = __expf(s);
                    eexp[b*200 + t0 + tl] = ex;
                    s_ex[tl] = ex;
                }
            }
            __syncthreads();
            if (tid == 0) {
                float s = 0.f;
                for (int i = 0; i < 25; ++i) s += s_ex[i];
                denp[b*8 + tc] = s;     // per-chunk partial, no atomics
            }
        }
        grid_barrier(flags, gen, ++bnum);

        // ---- S4: context = (e_exp @ memory)/den ; normalize att_w; cum; alignments ----
        {
            int b = blockIdx.x >> 3, dc = blockIdx.x & 7;
            float db = 0.f;
#pragma unroll
            for (int c = 0; c < 8; ++c) db += denp[b*8 + c];   // broadcast loads
            int dl = tid & 63, tq = tid >> 6;     // 16 t-chunks of 13
            int d = dc*64 + dl;
            float s = 0.f;
            int te = min(200, tq*13 + 13);
            for (int tt = tq*13; tt < te; ++tt)
                s = fmaf(eexp[b*200 + tt], mp[(b*200 + tt)*512 + d], s);
            s_red[tid] = s;
            __syncthreads();
            if (tid < 64) {
                float cv = 0.f;
#pragma unroll
                for (int q = 0; q < 16; ++q) cv += s_red[q*64 + tid];
                cv /= db;
                int dd = dc*64 + tid;
                ctx[b*512 + dd] = cv;
                in2T[(1024 + dd)*32 + b] = cv;
                in1T[(256 + dd)*32 + b] = cv;
            }
            if (dc == 0 && tid >= 512 && tid < 712) {
                int tt = tid - 512;
                float w = eexp[b*200 + tt] / db;
                attw[b*200 + tt] = w;
                cum[b*200 + tt] += w;
                out[OUT_ALIGN + (b*400 + t)*200 + tt] = w;
            }
        }
        grid_barrier(flags, gen, ++bnum);

        // ---- S5: LSTM2 gate partials ----
        gemv_block(l2k, l2r, KSPL2, in2T, zp, KC2);
        grid_barrier(flags, gen, ++bnum);

        // ---- S6: reduce -> h2,c2 ; projections ; stage x_{t+1} ----
        if (blockIdx.x < 32) {
            int b = blockIdx.x;
            {
                int u = tid;
                float zi = l2b[u], zf = l2b[1024+u], zg = l2b[2048+u], zo = l2b[3072+u];
#pragma unroll 8
                for (int kc = 0; kc < 16; ++kc) {
                    const float* zr = zp + (kc*32 + b)*4096;
                    zi += zr[u]; zf += zr[1024+u]; zg += zr[2048+u]; zo += zr[3072+u];
                }
                float c = sigf(zf)*c2a[b*1024+u] + sigf(zi)*tanhf_(zg);
                float h = sigf(zo)*tanhf_(c);
                c2a[b*1024+u] = c;
                in2T[(1536+u)*32 + b] = h;
                s_hid[u] = h;
            }
            __syncthreads();
            if (tid < 240) {
                int kq = tid / 80, m = tid % 80;
                float part = 0.f;
                for (int k = kq*512; k < kq*512 + 512; ++k) {
                    float dv = (k < 1024) ? s_hid[k] : ctx[b*512 + (k - 1024)];
                    part = fmaf(dv, fw[k*80 + m], part);
                }
                s_red[tid] = part;
            }
            __syncthreads();
            if (tid < 80)
                out[(b*80 + tid)*400 + t] = fb[tid] + s_red[tid] + s_red[80+tid] + s_red[160+tid];
            if (tid >= 256 && tid < 320) {          // stop gate (separate wave)
                int ln = tid - 256;
                float sp = 0.f;
                for (int k = ln; k < 1536; k += 64) {
                    float dv = (k < 1024) ? s_hid[k] : ctx[b*512 + (k - 1024)];
                    sp = fmaf(dv, sw[k], sp);
                }
                for (int off = 32; off; off >>= 1) sp += __shfl_down(sp, off, 64);
                if (ln == 0) out[OUT_GATE + b*400 + t] = sigf(sp + sb[0]);
            }
        } else if (blockIdx.x < 64) {
            int b = blockIdx.x - 32;
            if (t + 1 < TSTEPS && tid < 256)
                in1T[tid*32 + b] = xpre[((t+1)*32 + b)*256 + tid];
        }
        grid_barrier(flags, gen, ++bnum);
    }
}

extern "C" void kernel_launch(void* const* d_in, const int* in_sizes, int n_in,
                              void* d_out, int out_size, void* d_ws, size_t ws_size,
                              hipStream_t stream) {
    (void)in_sizes; (void)n_in; (void)out_size;
    const float* mp    = (const float*)d_in[0];
    const float* dec   = (const float*)d_in[1];
    const float* pw0   = (const float*)d_in[2];
    const float* pb0   = (const float*)d_in[3];
    const float* pw1   = (const float*)d_in[4];
    const float* pb1   = (const float*)d_in[5];
    const float* l1k   = (const float*)d_in[6];
    const float* l1r   = (const float*)d_in[7];
    const float* l1b   = (const float*)d_in[8];
    const float* l2k   = (const float*)d_in[9];
    const float* l2r   = (const float*)d_in[10];
    const float* l2b   = (const float*)d_in[11];
    const float* wq    = (const float*)d_in[12];
    const float* wm    = (const float*)d_in[13];
    const float* vvec  = (const float*)d_in[14];
    const float* lconv = (const float*)d_in[15];
    const float* ldns  = (const float*)d_in[16];
    const float* fw    = (const float*)d_in[17];
    const float* fb    = (const float*)d_in[18];
    const float* sw    = (const float*)d_in[19];
    const float* sb    = (const float*)d_in[20];
    float* ws  = (float*)d_ws;
    float* out = (float*)d_out;

    if (ws_size < (size_t)WS_FLOATS * sizeof(float)) return;

    prenet_kernel<<<dim3(400, 32), 256, 0, stream>>>(dec, pw0, pb0, pw1, pb1, ws);
    pmem_kernel  <<<dim3(200, 32), 128, 0, stream>>>(mp, wm, ws);
    decoder_loop <<<NBLK, NTHR, 0, stream>>>(mp, l1k, l1r, l1b, l2k, l2r, l2b,
                                             wq, vvec, lconv, ldns, fw, fb, sw, sb, ws, out);
}

// Round 4
// 169286.340 us; speedup vs baseline: 2.8019x; 2.8019x over previous
//
#include <hip/hip_runtime.h>
#include <math.h>

// ---------------- problem constants ----------------
#define TSTEPS 400
#define NBLK 256
#define NTHR 1024

// GEMV1: K1=1792 (x 0..255 | ctx 256..767 | h1 768..1791), ksplit=768
//   224 blocks = 32 colgrp(128 cols) x 7 ksp(256 k)  -> zp slots 0..6
// GEMV2: K2=2560 (h1 0..1023 | ctx 1024..1535 | h2 1536..2559), ksplit=1536
//   256 blocks = 32 colgrp(128 cols) x 8 ksp(320 k)  -> zp slots 7..14

// ---------------- workspace layout (float offsets) ----------------
#define OFF_XPRE  0u
#define SZ_XPRE   (400u*256u*32u)          // prenet outputs TRANSPOSED [t][k][b]
#define OFF_PM    (OFF_XPRE + SZ_XPRE)
#define SZ_PM     (32u*200u*128u)          // tanh(memory@wm) [b][t][128]
#define OFF_IN1T  (OFF_PM + SZ_PM)
#define SZ_IN1T   (1792u*32u)              // lstm1 input rows [k][b] (rows 0..255 unused; x comes from xpre)
#define OFF_IN2T  (OFF_IN1T + SZ_IN1T)
#define SZ_IN2T   (2560u*32u)              // lstm2 input rows [k][b]
#define OFF_ZP    (OFF_IN2T + SZ_IN2T)
#define SZ_ZP     (15u*32u*4096u)          // 15 slots: gemv1 ksp 0..6, gemv2 ksp 7..14
#define OFF_CTXP  (OFF_ZP + SZ_ZP)
#define SZ_CTXP   (2u*32u*512u)            // ctx double-buffer [parity][b][512]
#define OFF_CNT   (OFF_CTXP + SZ_CTXP)     // barrier: 16 group cnts + root cnt + gen (128B lines)
#define SZ_CNT    (18u*32u)
#define WS_FLOATS (OFF_CNT + SZ_CNT)       // ~6.23M floats = 24.9 MB (<= proven-available 26.1 MB)

// output layout (floats)
#define OUT_GATE  1024000   // 32*80*400
#define OUT_ALIGN 1036800   // + 32*400

__device__ __forceinline__ float sigf(float x)   { return 1.f / (1.f + __expf(-x)); }
__device__ __forceinline__ float tanhf_(float x) { return 1.f - 2.f / (__expf(2.f*x) + 1.f); }

// ---------------- tree grid barrier ----------------
// Cumulative counters (no reset). 16 groups x 16 blocks: 16 parallel RMW chains
// of 16 (~3us) + one 16-chain at root. RELAXED RMWs and RELAXED polls; exactly
// one release fence before arrival and one acquire fence after exit, by tid0
// only (R1-proven pattern; R3 showed per-iteration ACQUIRE polls are 3x slower).
__device__ __forceinline__ void grid_barrier(unsigned* cnt, unsigned n) {
    __syncthreads();
    if (threadIdx.x == 0) {
        __threadfence();   // release our phase's writes
        unsigned grp = blockIdx.x >> 4;
        unsigned old = __hip_atomic_fetch_add(cnt + grp*32, 1u, __ATOMIC_RELAXED, __HIP_MEMORY_SCOPE_AGENT);
        if (old == 16u*n - 1u) {           // last of this group's 16 for barrier n
            unsigned r = __hip_atomic_fetch_add(cnt + 16*32, 1u, __ATOMIC_RELAXED, __HIP_MEMORY_SCOPE_AGENT);
            if (r == 16u*n - 1u)           // last group
                __hip_atomic_store(cnt + 17*32, n, __ATOMIC_RELEASE, __HIP_MEMORY_SCOPE_AGENT);
        }
        while (__hip_atomic_load(cnt + 17*32, __ATOMIC_RELAXED, __HIP_MEMORY_SCOPE_AGENT) < n)
            __builtin_amdgcn_s_sleep(8);
        __threadfence();   // acquire: drop stale lines
    }
    __syncthreads();
}

// ---------------- P1: prenet for all 400 frames (transposed out) ----------------
__global__ void __launch_bounds__(256) prenet_kernel(
    const float* __restrict__ dec, const float* __restrict__ w0, const float* __restrict__ b0,
    const float* __restrict__ w1, const float* __restrict__ b1, float* __restrict__ ws)
{
    __shared__ float s_in[80];
    __shared__ float s_h0[256];
    int t = blockIdx.x, b = blockIdx.y, tid = threadIdx.x;
    if (tid < 80) s_in[tid] = (t == 0) ? 0.f : dec[b*32000 + tid*400 + (t-1)];
    if (blockIdx.x == 0 && blockIdx.y == 0) {
        unsigned* bw = (unsigned*)(ws + OFF_CNT);
        for (int i = tid; i < (int)SZ_CNT; i += 256) bw[i] = 0u;
    }
    __syncthreads();
    float s = b0[tid];
    for (int m = 0; m < 80; ++m) s = fmaf(s_in[m], w0[m*256 + tid], s);
    s_h0[tid] = fmaxf(s, 0.f);
    __syncthreads();
    float s2 = b1[tid];
    for (int k = 0; k < 256; ++k) s2 = fmaf(s_h0[k], w1[k*256 + tid], s2);
    ws[OFF_XPRE + t*8192 + tid*32 + b] = fmaxf(s2, 0.f);   // [t][k][b]
}

// ---------------- P2: processed_memory = tanh(memory @ wm) ----------------
__global__ void __launch_bounds__(128) pmem_kernel(
    const float* __restrict__ mp, const float* __restrict__ wm, float* __restrict__ ws)
{
    int t = blockIdx.x, b = blockIdx.y, a = threadIdx.x;
    const float* mrow = mp + (b*200 + t)*512;
    float s = 0.f;
    for (int d = 0; d < 512; ++d) s = fmaf(mrow[d], wm[d*128 + a], s);
    ws[OFF_PM + (b*200 + t)*128 + a] = tanhf_(s);
}

// ---------------- GEMV partial: one (colgrp, ksp) tile ----------------
// thread: jq = tid&31 (32 float4 = 128 cols), b = tid>>5. Per k: 1 float4
// weight load (512B/half-wave, coalesced) + 1 broadcast x load, 4 FMA.
__device__ __forceinline__ void gemv_part(
    const float* __restrict__ Wk, const float* __restrict__ Wr, int ksplit,
    const float* __restrict__ inT, float* __restrict__ zslot, int j0, int k0, int klen)
{
    const int jq = threadIdx.x & 31;
    const int b  = threadIdx.x >> 5;
    const int j  = j0 + (jq << 2);
    float4 acc = {0.f, 0.f, 0.f, 0.f};
    const int kend = k0 + klen;
    const int ka = min(kend, ksplit);
#pragma unroll 8
    for (int k = k0; k < ka; ++k) {
        float4 w = *(const float4*)(Wk + k*4096 + j);
        float  x = inT[k*32 + b];
        acc.x = fmaf(x, w.x, acc.x); acc.y = fmaf(x, w.y, acc.y);
        acc.z = fmaf(x, w.z, acc.z); acc.w = fmaf(x, w.w, acc.w);
    }
    const int kb = max(k0, ksplit);
#pragma unroll 8
    for (int k = kb; k < kend; ++k) {
        float4 w = *(const float4*)(Wr + (k - ksplit)*4096 + j);
        float  x = inT[k*32 + b];
        acc.x = fmaf(x, w.x, acc.x); acc.y = fmaf(x, w.y, acc.y);
        acc.z = fmaf(x, w.z, acc.z); acc.w = fmaf(x, w.w, acc.w);
    }
    *(float4*)(zslot + b*4096 + j) = acc;
}

// ---------------- persistent decoder loop ----------------
__global__ void __launch_bounds__(NTHR, 4) decoder_loop(
    const float* __restrict__ mp,
    const float* __restrict__ l1k, const float* __restrict__ l1r, const float* __restrict__ l1b,
    const float* __restrict__ l2k, const float* __restrict__ l2r, const float* __restrict__ l2b,
    const float* __restrict__ wq, const float* __restrict__ vvec,
    const float* __restrict__ lconv, const float* __restrict__ ldense,
    const float* __restrict__ fw, const float* __restrict__ fb,
    const float* __restrict__ sw, const float* __restrict__ sb,
    float* __restrict__ ws, float* __restrict__ out)
{
    // persistent per-block state (blocks 0..31 own batch b = blockIdx.x)
    __shared__ float s_attw[200], s_cum[200];   // attention weights / cumulative (persist all steps)
    __shared__ float s_c1[1024], s_c2[1024];    // LSTM cell states (persist)
    // scratch
    __shared__ float s_hid[1024];
    __shared__ float s_q[128];
    __shared__ float s_ex[200];
    __shared__ float s_co[200*33];              // conv output, padded
    __shared__ float s_red[1024];
    __shared__ float s_den[1];

    float* xpre = ws + OFF_XPRE;
    float* pm   = ws + OFF_PM;
    float* in1T = ws + OFF_IN1T;
    float* in2T = ws + OFF_IN2T;
    float* zp   = ws + OFF_ZP;
    float* ctxp = ws + OFF_CTXP;
    unsigned* cnt = (unsigned*)(ws + OFF_CNT);
    unsigned bnum = 0;

    const int tid = threadIdx.x;
    const int bid = blockIdx.x;
    const int gid = bid * NTHR + tid;
    const int gsz = NBLK * NTHR;

    // ---- init (ws poisoned before every call) ----
    for (int i = gid + 256*32; i < (int)SZ_IN1T; i += gsz) in1T[i] = 0.f;  // ctx+h rows
    for (int i = gid; i < (int)SZ_IN2T; i += gsz) in2T[i] = 0.f;           // h1/ctx/h2 rows
    if (bid < 32) {
        if (tid < 200) { s_attw[tid] = 0.f; s_cum[tid] = 0.f; }
        s_c1[tid] = 0.f; s_c2[tid] = 0.f;
    }
    grid_barrier(cnt, ++bnum);

#pragma unroll 1
    for (int t = 0; t <= TSTEPS; ++t) {
        // ================= PHASE 1: gemv1_t (blocks 32..255)  ||  LSTM2 gates for t-1 (blocks 0..31)
        if (bid < 32) {
            if (t > 0) {
                int b = bid, u = tid;
                float zi = l2b[u], zf = l2b[1024+u], zg = l2b[2048+u], zo = l2b[3072+u];
#pragma unroll
                for (int kc = 0; kc < 8; ++kc) {
                    const float* zr = zp + ((7+kc)*32 + b)*4096;
                    zi += zr[u]; zf += zr[1024+u]; zg += zr[2048+u]; zo += zr[3072+u];
                }
                float c = sigf(zf)*s_c2[u] + sigf(zi)*tanhf_(zg);
                float h = sigf(zo)*tanhf_(c);
                s_c2[u] = c;
                in2T[(1536+u)*32 + b] = h;      // h2_{t-1} rows for gemv2_t and mel_{t-1}
            }
        } else if (t < TSTEPS) {
            int id = bid - 32;
            int colgrp = id & 31, ksp = id >> 5;       // 32 x 7
            const float* inT = (ksp == 0) ? (xpre + t*8192) : in1T;
            gemv_part(l1k, l1r, 768, inT, zp + (size_t)ksp*32*4096, colgrp*128, ksp*256, 256);
        }
        grid_barrier(cnt, ++bnum);

        // ================= PHASE 2: gates1 + attention + ctx (blocks 0..31, per-b)
        //                   ||  mel_{t-1} (32..41), stop-gate_{t-1} (42)
        if (bid < 32 && t < TSTEPS) {
            int b = bid;
            {   // LSTM1 gates
                int u = tid;
                float zi = l1b[u], zf = l1b[1024+u], zg = l1b[2048+u], zo = l1b[3072+u];
#pragma unroll
                for (int kc = 0; kc < 7; ++kc) {
                    const float* zr = zp + (kc*32 + b)*4096;
                    zi += zr[u]; zf += zr[1024+u]; zg += zr[2048+u]; zo += zr[3072+u];
                }
                float c = sigf(zf)*s_c1[u] + sigf(zi)*tanhf_(zg);
                float h = sigf(zo)*tanhf_(c);
                s_c1[u] = c;
                s_hid[u] = h;
                in1T[(768+u)*32 + b] = h;       // for gemv1_{t+1}
                in2T[u*32 + b] = h;             // for gemv2_t
            }
            __syncthreads();
            {   // q partials: 8 k-strips x 128 a
                int a = tid & 127, kq = tid >> 7;
                float s = 0.f;
                for (int k = kq*128; k < kq*128 + 128; ++k)
                    s = fmaf(s_hid[k], wq[k*128 + a], s);
                s_red[tid] = s;
            }
            __syncthreads();
            if (tid < 128) {
                float s = 0.f;
#pragma unroll
                for (int q = 0; q < 8; ++q) s += s_red[q*128 + tid];
                s_q[tid] = tanhf_(s);
            }
            // location conv (reads t-1 attw/cum from LDS)
            for (int idx = tid; idx < 6400; idx += NTHR) {
                int tl = idx >> 5, f = idx & 31;
                float s = 0.f;
                for (int dw = 0; dw < 31; ++dw) {
                    int tg = tl - 15 + dw;
                    if (tg >= 0 && tg < 200) {
                        s = fmaf(s_attw[tg], lconv[(dw*2+0)*32 + f], s);
                        s = fmaf(s_cum[tg],  lconv[(dw*2+1)*32 + f], s);
                    }
                }
                s_co[tl*33 + f] = s;
            }
            __syncthreads();
            // energies: 200 t x 4 lanes x 32 a
            if (tid < 800) {
                int tl = tid >> 2, aq = tid & 3;
                const float* pmrow = pm + (b*200 + tl)*128;
                float e = 0.f;
                for (int a = aq*32; a < aq*32 + 32; ++a) {
                    float s = 0.f;
#pragma unroll
                    for (int f = 0; f < 32; ++f) s = fmaf(s_co[tl*33 + f], ldense[f*128 + a], s);
                    float en = tanhf_(s_q[a] + tanhf_(s) + pmrow[a]);
                    e = fmaf(en, vvec[a], e);
                }
                e += __shfl_xor(e, 1, 4);
                e += __shfl_xor(e, 2, 4);
                if (aq == 0) s_ex[tl] = __expf(e);   // |e| <= ||v||_1 ~ 5: exp safe
            }
            __syncthreads();
            if (tid < 64) {
                float s = 0.f;
                for (int i = tid; i < 200; i += 64) s += s_ex[i];
                for (int off = 32; off; off >>= 1) s += __shfl_down(s, off, 64);
                if (tid == 0) s_den[0] = s;
            }
            __syncthreads();
            if (tid < 200) {
                float w = s_ex[tid] / s_den[0];
                s_attw[tid] = w;
                s_cum[tid] += w;
                out[OUT_ALIGN + (b*400 + t)*200 + tid] = w;
            }
            __syncthreads();
            {   // context = att_w @ memory
                int d = tid & 511, th = tid >> 9;
                float s = 0.f;
                for (int tt = th*100; tt < th*100 + 100; ++tt)
                    s = fmaf(s_attw[tt], mp[(b*200 + tt)*512 + d], s);
                s_red[tid] = s;
            }
            __syncthreads();
            if (tid < 512) {
                float cv = s_red[tid] + s_red[512 + tid];
                ctxp[(t & 1)*16384 + b*512 + tid] = cv;
                in1T[(256 + tid)*32 + b] = cv;     // for gemv1_{t+1}
                in2T[(1024 + tid)*32 + b] = cv;    // for gemv2_t
            }
        } else if (bid >= 32 && bid < 42 && t > 0) {
            // mel for step t-1: 10 blocks x 8 mel-ch each; h2_{t-1} from phase1
            int mc = bid - 32, t1 = t - 1;
            int m_l = tid & 7, b = (tid >> 3) & 31, kh = tid >> 8;
            int m = mc*8 + m_l;
            const float* cp = ctxp + ((t1 & 1)*32 + b)*512;
            float s = 0.f;
            for (int k = kh*384; k < kh*384 + 384; ++k) {
                float dv = (k < 1024) ? in2T[(1536+k)*32 + b] : cp[k - 1024];
                s = fmaf(dv, fw[k*80 + m], s);
            }
            s_red[tid] = s;
            __syncthreads();
            if (tid < 256) {
                float v4 = s_red[tid] + s_red[256+tid] + s_red[512+tid] + s_red[768+tid];
                int b2 = tid >> 3, m2 = mc*8 + (tid & 7);
                out[(b2*80 + m2)*400 + t1] = v4 + fb[m2];
            }
        } else if (bid == 42 && t > 0) {
            // stop gate for t-1
            int t1 = t - 1;
            int b = tid >> 5, kh = tid & 31;
            const float* cp = ctxp + ((t1 & 1)*32 + b)*512;
            float s = 0.f;
            for (int k = kh*48; k < kh*48 + 48; ++k) {
                float dv = (k < 1024) ? in2T[(1536+k)*32 + b] : cp[k - 1024];
                s = fmaf(dv, sw[k], s);
            }
            s_red[b*32 + kh] = s;
            __syncthreads();
            if (tid < 32) {
                float z = 0.f;
#pragma unroll
                for (int i = 0; i < 32; ++i) z += s_red[tid*32 + i];
                out[OUT_GATE + tid*400 + t1] = sigf(z + sb[0]);
            }
        }
        grid_barrier(cnt, ++bnum);

        // ================= PHASE 3: gemv2_t (all 256 blocks)
        if (t < TSTEPS) {
            int colgrp = bid & 31, ksp = bid >> 5;     // 32 x 8
            gemv_part(l2k, l2r, 1536, in2T, zp + (size_t)(7 + ksp)*32*4096, colgrp*128, ksp*320, 320);
        }
        grid_barrier(cnt, ++bnum);
    }
}

extern "C" void kernel_launch(void* const* d_in, const int* in_sizes, int n_in,
                              void* d_out, int out_size, void* d_ws, size_t ws_size,
                              hipStream_t stream) {
    (void)in_sizes; (void)n_in; (void)out_size;
    const float* mp    = (const float*)d_in[0];
    const float* dec   = (const float*)d_in[1];
    const float* pw0   = (const float*)d_in[2];
    const float* pb0   = (const float*)d_in[3];
    const float* pw1   = (const float*)d_in[4];
    const float* pb1   = (const float*)d_in[5];
    const float* l1k   = (const float*)d_in[6];
    const float* l1r   = (const float*)d_in[7];
    const float* l1b   = (const float*)d_in[8];
    const float* l2k   = (const float*)d_in[9];
    const float* l2r   = (const float*)d_in[10];
    const float* l2b   = (const float*)d_in[11];
    const float* wq    = (const float*)d_in[12];
    const float* wm    = (const float*)d_in[13];
    const float* vvec  = (const float*)d_in[14];
    const float* lconv = (const float*)d_in[15];
    const float* ldns  = (const float*)d_in[16];
    const float* fw    = (const float*)d_in[17];
    const float* fb    = (const float*)d_in[18];
    const float* sw    = (const float*)d_in[19];
    const float* sb    = (const float*)d_in[20];
    float* ws  = (float*)d_ws;
    float* out = (float*)d_out;

    if (ws_size < (size_t)WS_FLOATS * sizeof(float)) return;

    prenet_kernel<<<dim3(400, 32), 256, 0, stream>>>(dec, pw0, pb0, pw1, pb1, ws);
    pmem_kernel  <<<dim3(200, 32), 128, 0, stream>>>(mp, wm, ws);
    decoder_loop <<<NBLK, NTHR, 0, stream>>>(mp, l1k, l1r, l1b, l2k, l2r, l2b,
                                             wq, vvec, lconv, ldns, fw, fb, sw, sb, ws, out);
}

// Round 5
// 111364.160 us; speedup vs baseline: 4.2592x; 1.5201x over previous
//
#include <hip/hip_runtime.h>
#include <math.h>

// ---------------- problem constants ----------------
#define TSTEPS 400

// GEMV1: K1=1792 (x 0..255 bf16 | ctx 256..767 | h1 768..1791), W split at 768
//   112 blocks = 16 colgrp(256 cols) x 7 ksp(256 k = 2 ksub x 128)
// GEMV2: K2=2560 (h1 0..1023 | ctx 1024..1535 | h2 1536..2559), W split at 1536
//   128 blocks = 16 colgrp(256 cols) x 8 ksp(320 k = 2 ksub x 160)
#define KSP1 7
#define KSP2 8

// ---------------- workspace layout (float offsets) ----------------
#define OFF_XPRE  0u          // prenet out, BF16 [t][k][b]: 400*256*32 ushort = 1,638,400 float-slots
#define OFF_PM    1638400u    // tanh(memory@wm) fp32 [b][t][128]  (819,200)
#define OFF_IN1T  2457600u    // lstm1 input rows 256..1791, [(k-256)][b] (49,152)
#define OFF_IN2T  2506752u    // lstm2 input rows [k][b] (81,920)
#define OFF_ZP1   2588672u    // gemv1 partials [7][32][4096] (917,504)
#define OFF_ZP2   3506176u    // gemv2 partials [8][32][4096] (1,048,576)
#define OFF_CTXP  4554752u    // ctx double buffer [parity][b][512] (32,768)
#define OFF_C1    4587520u    // c1 [b][1024] (32,768)
#define OFF_C2    4620288u    // c2 (32,768)
#define OFF_ATTW  4653056u    // att_w [b][200] (6,400)
#define OFF_CUM   4659456u    // att_w_cum (6,400)
#define WS_FLOATS 4665856u    // 18.66 MB (<= proven-available 24.9 MB)

// output layout (floats)
#define OUT_GATE  1024000   // 32*80*400
#define OUT_ALIGN 1036800   // + 32*400

__device__ __forceinline__ float sigf(float x)   { return 1.f / (1.f + __expf(-x)); }
__device__ __forceinline__ float tanhf_(float x) { return 1.f - 2.f / (__expf(2.f*x) + 1.f); }

// ---------------- P1: prenet for all 400 frames -> bf16 [t][k][b] ----------------
__global__ void __launch_bounds__(256) prenet_kernel(
    const float* __restrict__ dec, const float* __restrict__ w0, const float* __restrict__ b0,
    const float* __restrict__ w1, const float* __restrict__ b1, float* __restrict__ ws)
{
    __shared__ float s_in[80];
    __shared__ float s_h0[256];
    int t = blockIdx.x, b = blockIdx.y, tid = threadIdx.x;
    if (tid < 80) s_in[tid] = (t == 0) ? 0.f : dec[b*32000 + tid*400 + (t-1)];
    __syncthreads();
    float s = b0[tid];
    for (int m = 0; m < 80; ++m) s = fmaf(s_in[m], w0[m*256 + tid], s);
    s_h0[tid] = fmaxf(s, 0.f);
    __syncthreads();
    float s2 = b1[tid];
    for (int k = 0; k < 256; ++k) s2 = fmaf(s_h0[k], w1[k*256 + tid], s2);
    float v = fmaxf(s2, 0.f);
    unsigned u = __float_as_uint(v);
    u += 0x7fffu + ((u >> 16) & 1u);                     // RNE to bf16
    ((unsigned short*)(ws + OFF_XPRE))[(size_t)t*8192 + tid*32 + b] = (unsigned short)(u >> 16);
}

// ---------------- P2: processed_memory = tanh(memory @ wm), fp32 ----------------
__global__ void __launch_bounds__(128) pmem_kernel(
    const float* __restrict__ mp, const float* __restrict__ wm, float* __restrict__ ws)
{
    int t = blockIdx.x, b = blockIdx.y, a = threadIdx.x;
    const float* mrow = mp + (b*200 + t)*512;
    float s = 0.f;
    for (int d = 0; d < 512; ++d) s = fmaf(mrow[d], wm[d*128 + a], s);
    ws[OFF_PM + (b*200 + t)*128 + a] = tanhf_(s);
}

// ---------------- P3: zero recurrent state ----------------
__global__ void __launch_bounds__(256) zero_kernel(float* __restrict__ ws)
{
    int gid = blockIdx.x*256 + threadIdx.x, gsz = gridDim.x*256;
    for (int i = gid; i < 49152; i += gsz) ws[OFF_IN1T + i] = 0.f;
    for (int i = gid; i < 81920; i += gsz) ws[OFF_IN2T + i] = 0.f;
    for (int i = gid; i < 32768; i += gsz) { ws[OFF_C1 + i] = 0.f; ws[OFF_C2 + i] = 0.f; }
    for (int i = gid; i < 6400;  i += gsz) { ws[OFF_ATTW + i] = 0.f; ws[OFF_CUM + i] = 0.f; }
}

// ---------------- K_A: gemv1(t) [blocks 0..111]  ||  LSTM2 gates(t-1) [112..143] ----------------
// gemv thread: 4 cols (float4 w) x 8 batches (outer product, 32 acc VGPRs).
// Weight line read by 4 waves (not 32 threads) -> L1 redundancy 32x -> 4x.
__global__ void __launch_bounds__(512) kernel_A(
    const float* __restrict__ l1k, const float* __restrict__ l1r,
    const float* __restrict__ l2b, float* __restrict__ ws, int t)
{
    const int tid = threadIdx.x, bid = blockIdx.x;
    if (bid < 112) {
        if (t >= TSTEPS) return;
        __shared__ float s_acc[8192];
        float* zp1 = ws + OFF_ZP1;
        const float* in1m = ws + OFF_IN1T - 8192;   // valid for k >= 256
        const int colgrp = bid & 15, ksp = bid >> 4;
        const int jq = tid & 63, bgrp = (tid >> 6) & 3, ksub = tid >> 8;
        const int j = colgrp*256 + jq*4;
        const int b0 = bgrp*8;
        float4 a[8];
#pragma unroll
        for (int i = 0; i < 8; ++i) a[i] = make_float4(0.f, 0.f, 0.f, 0.f);
        const int k0 = ksp*256 + ksub*128;
        if (ksp == 0) {
            const unsigned short* xp = (const unsigned short*)(ws + OFF_XPRE) + (size_t)t*8192;
#pragma unroll 2
            for (int k = k0; k < k0 + 128; ++k) {
                float4 w = *(const float4*)(l1k + (size_t)k*4096 + j);
                uint4 xr = *(const uint4*)(xp + k*32 + b0);
                const unsigned short* xs = (const unsigned short*)&xr;
#pragma unroll
                for (int i = 0; i < 8; ++i) {
                    float x = __uint_as_float(((unsigned)xs[i]) << 16);
                    a[i].x = fmaf(x, w.x, a[i].x); a[i].y = fmaf(x, w.y, a[i].y);
                    a[i].z = fmaf(x, w.z, a[i].z); a[i].w = fmaf(x, w.w, a[i].w);
                }
            }
        } else {
            const int kend = k0 + 128;
            const int ka = min(kend, 768);
#pragma unroll 2
            for (int k = k0; k < ka; ++k) {
                float4 w = *(const float4*)(l1k + (size_t)k*4096 + j);
                float4 xa = *(const float4*)(in1m + k*32 + b0);
                float4 xb = *(const float4*)(in1m + k*32 + b0 + 4);
                a[0].x = fmaf(xa.x, w.x, a[0].x); a[0].y = fmaf(xa.x, w.y, a[0].y); a[0].z = fmaf(xa.x, w.z, a[0].z); a[0].w = fmaf(xa.x, w.w, a[0].w);
                a[1].x = fmaf(xa.y, w.x, a[1].x); a[1].y = fmaf(xa.y, w.y, a[1].y); a[1].z = fmaf(xa.y, w.z, a[1].z); a[1].w = fmaf(xa.y, w.w, a[1].w);
                a[2].x = fmaf(xa.z, w.x, a[2].x); a[2].y = fmaf(xa.z, w.y, a[2].y); a[2].z = fmaf(xa.z, w.z, a[2].z); a[2].w = fmaf(xa.z, w.w, a[2].w);
                a[3].x = fmaf(xa.w, w.x, a[3].x); a[3].y = fmaf(xa.w, w.y, a[3].y); a[3].z = fmaf(xa.w, w.z, a[3].z); a[3].w = fmaf(xa.w, w.w, a[3].w);
                a[4].x = fmaf(xb.x, w.x, a[4].x); a[4].y = fmaf(xb.x, w.y, a[4].y); a[4].z = fmaf(xb.x, w.z, a[4].z); a[4].w = fmaf(xb.x, w.w, a[4].w);
                a[5].x = fmaf(xb.y, w.x, a[5].x); a[5].y = fmaf(xb.y, w.y, a[5].y); a[5].z = fmaf(xb.y, w.z, a[5].z); a[5].w = fmaf(xb.y, w.w, a[5].w);
                a[6].x = fmaf(xb.z, w.x, a[6].x); a[6].y = fmaf(xb.z, w.y, a[6].y); a[6].z = fmaf(xb.z, w.z, a[6].z); a[6].w = fmaf(xb.z, w.w, a[6].w);
                a[7].x = fmaf(xb.w, w.x, a[7].x); a[7].y = fmaf(xb.w, w.y, a[7].y); a[7].z = fmaf(xb.w, w.z, a[7].z); a[7].w = fmaf(xb.w, w.w, a[7].w);
            }
            const int kb = max(k0, 768);
#pragma unroll 2
            for (int k = kb; k < kend; ++k) {
                float4 w = *(const float4*)(l1r + (size_t)(k - 768)*4096 + j);
                float4 xa = *(const float4*)(in1m + k*32 + b0);
                float4 xb = *(const float4*)(in1m + k*32 + b0 + 4);
                a[0].x = fmaf(xa.x, w.x, a[0].x); a[0].y = fmaf(xa.x, w.y, a[0].y); a[0].z = fmaf(xa.x, w.z, a[0].z); a[0].w = fmaf(xa.x, w.w, a[0].w);
                a[1].x = fmaf(xa.y, w.x, a[1].x); a[1].y = fmaf(xa.y, w.y, a[1].y); a[1].z = fmaf(xa.y, w.z, a[1].z); a[1].w = fmaf(xa.y, w.w, a[1].w);
                a[2].x = fmaf(xa.z, w.x, a[2].x); a[2].y = fmaf(xa.z, w.y, a[2].y); a[2].z = fmaf(xa.z, w.z, a[2].z); a[2].w = fmaf(xa.z, w.w, a[2].w);
                a[3].x = fmaf(xa.w, w.x, a[3].x); a[3].y = fmaf(xa.w, w.y, a[3].y); a[3].z = fmaf(xa.w, w.z, a[3].z); a[3].w = fmaf(xa.w, w.w, a[3].w);
                a[4].x = fmaf(xb.x, w.x, a[4].x); a[4].y = fmaf(xb.x, w.y, a[4].y); a[4].z = fmaf(xb.x, w.z, a[4].z); a[4].w = fmaf(xb.x, w.w, a[4].w);
                a[5].x = fmaf(xb.y, w.x, a[5].x); a[5].y = fmaf(xb.y, w.y, a[5].y); a[5].z = fmaf(xb.y, w.z, a[5].z); a[5].w = fmaf(xb.y, w.w, a[5].w);
                a[6].x = fmaf(xb.z, w.x, a[6].x); a[6].y = fmaf(xb.z, w.y, a[6].y); a[6].z = fmaf(xb.z, w.z, a[6].z); a[6].w = fmaf(xb.z, w.w, a[6].w);
                a[7].x = fmaf(xb.w, w.x, a[7].x); a[7].y = fmaf(xb.w, w.y, a[7].y); a[7].z = fmaf(xb.w, w.z, a[7].z); a[7].w = fmaf(xb.w, w.w, a[7].w);
            }
        }
        if (ksub == 1) {
#pragma unroll
            for (int i = 0; i < 8; ++i)
                *(float4*)(s_acc + (b0 + i)*256 + jq*4) = a[i];
        }
        __syncthreads();
        if (ksub == 0) {
#pragma unroll
            for (int i = 0; i < 8; ++i) {
                float4 r = *(const float4*)(s_acc + (b0 + i)*256 + jq*4);
                a[i].x += r.x; a[i].y += r.y; a[i].z += r.z; a[i].w += r.w;
                *(float4*)(zp1 + (size_t)(ksp*32 + b0 + i)*4096 + j) = a[i];
            }
        }
    } else {
        if (t == 0) return;
        const int b = bid - 112;
        float* zp2 = ws + OFF_ZP2;
        float* c2a = ws + OFF_C2;
        float* in2T = ws + OFF_IN2T;
        for (int u = tid; u < 1024; u += 512) {
            float zi = l2b[u], zf = l2b[1024+u], zg = l2b[2048+u], zo = l2b[3072+u];
#pragma unroll
            for (int kc = 0; kc < KSP2; ++kc) {
                const float* zr = zp2 + (size_t)(kc*32 + b)*4096;
                zi += zr[u]; zf += zr[1024+u]; zg += zr[2048+u]; zo += zr[3072+u];
            }
            float c = sigf(zf)*c2a[b*1024+u] + sigf(zi)*tanhf_(zg);
            float h = sigf(zo)*tanhf_(c);
            c2a[b*1024+u] = c;
            in2T[(1536+u)*32 + b] = h;
        }
    }
}

// ---------------- K_B: gates1+attention+ctx(t) [0..31] || mel(t-1) [32..41], stop(t-1) [42] ----------------
__global__ void __launch_bounds__(1024) kernel_B(
    const float* __restrict__ mp, const float* __restrict__ l1b,
    const float* __restrict__ wq, const float* __restrict__ vvec,
    const float* __restrict__ lconv, const float* __restrict__ ldense,
    const float* __restrict__ fw, const float* __restrict__ fb,
    const float* __restrict__ sw, const float* __restrict__ sb,
    float* __restrict__ ws, float* __restrict__ out, int t)
{
    __shared__ float s_attw[200], s_cum[200];
    __shared__ float s_hid[1024], s_q[128], s_ex[200], s_den[1];
    __shared__ float s_co[200*33];
    __shared__ float s_red[1024];
    const int tid = threadIdx.x, bid = blockIdx.x;
    float* in1m = ws + OFF_IN1T - 8192;
    float* in2T = ws + OFF_IN2T;
    float* zp1  = ws + OFF_ZP1;
    float* ctxp = ws + OFF_CTXP;
    float* c1a  = ws + OFF_C1;
    float* attw = ws + OFF_ATTW;
    float* cum  = ws + OFF_CUM;
    const float* pm = ws + OFF_PM;

    if (bid < 32) {
        if (t >= TSTEPS) return;
        const int b = bid;
        {   // LSTM1 gates
            int u = tid;
            float zi = l1b[u], zf = l1b[1024+u], zg = l1b[2048+u], zo = l1b[3072+u];
#pragma unroll
            for (int kc = 0; kc < KSP1; ++kc) {
                const float* zr = zp1 + (size_t)(kc*32 + b)*4096;
                zi += zr[u]; zf += zr[1024+u]; zg += zr[2048+u]; zo += zr[3072+u];
            }
            float c = sigf(zf)*c1a[b*1024+u] + sigf(zi)*tanhf_(zg);
            float h = sigf(zo)*tanhf_(c);
            c1a[b*1024+u] = c;
            s_hid[u] = h;
            in1m[(768+u)*32 + b] = h;       // for gemv1_{t+1}
            in2T[u*32 + b] = h;             // for gemv2_t
        }
        if (tid < 200) { s_attw[tid] = attw[b*200 + tid]; s_cum[tid] = cum[b*200 + tid]; }
        __syncthreads();
        {   // q partials: 8 k-strips x 128 a
            int a = tid & 127, kq = tid >> 7;
            float s = 0.f;
            for (int k = kq*128; k < kq*128 + 128; ++k)
                s = fmaf(s_hid[k], wq[k*128 + a], s);
            s_red[tid] = s;
        }
        __syncthreads();
        if (tid < 128) {
            float s = 0.f;
#pragma unroll
            for (int q = 0; q < 8; ++q) s += s_red[q*128 + tid];
            s_q[tid] = tanhf_(s);
        }
        // location conv (t-1 attw/cum from LDS)
        for (int idx = tid; idx < 6400; idx += 1024) {
            int tl = idx >> 5, f = idx & 31;
            float s = 0.f;
            for (int dw = 0; dw < 31; ++dw) {
                int tg = tl - 15 + dw;
                if (tg >= 0 && tg < 200) {
                    s = fmaf(s_attw[tg], lconv[(dw*2+0)*32 + f], s);
                    s = fmaf(s_cum[tg],  lconv[(dw*2+1)*32 + f], s);
                }
            }
            s_co[tl*33 + f] = s;
        }
        __syncthreads();
        // energies: 200 t x 4 lanes x 32 a
        if (tid < 800) {
            int tl = tid >> 2, aq = tid & 3;
            const float* pmrow = pm + (b*200 + tl)*128;
            float e = 0.f;
            for (int a = aq*32; a < aq*32 + 32; ++a) {
                float s = 0.f;
#pragma unroll
                for (int f = 0; f < 32; ++f) s = fmaf(s_co[tl*33 + f], ldense[f*128 + a], s);
                float en = tanhf_(s_q[a] + tanhf_(s) + pmrow[a]);
                e = fmaf(en, vvec[a], e);
            }
            e += __shfl_xor(e, 1, 4);
            e += __shfl_xor(e, 2, 4);
            if (aq == 0) s_ex[tl] = __expf(e);   // |e| <= ||v||_1 ~ 5: exp safe
        }
        __syncthreads();
        if (tid < 64) {
            float s = 0.f;
            for (int i = tid; i < 200; i += 64) s += s_ex[i];
            for (int off = 32; off; off >>= 1) s += __shfl_down(s, off, 64);
            if (tid == 0) s_den[0] = s;
        }
        __syncthreads();
        if (tid < 200) {
            float w = s_ex[tid] / s_den[0];
            s_attw[tid] = w;
            attw[b*200 + tid] = w;
            cum[b*200 + tid] = s_cum[tid] + w;
            out[OUT_ALIGN + (b*400 + t)*200 + tid] = w;
        }
        __syncthreads();
        {   // context = att_w @ memory
            int d = tid & 511, th = tid >> 9;
            float s = 0.f;
            for (int tt = th*100; tt < th*100 + 100; ++tt)
                s = fmaf(s_attw[tt], mp[(b*200 + tt)*512 + d], s);
            s_red[tid] = s;
        }
        __syncthreads();
        if (tid < 512) {
            float cv = s_red[tid] + s_red[512 + tid];
            ctxp[(t & 1)*16384 + b*512 + tid] = cv;
            in1m[(256 + tid)*32 + b] = cv;     // for gemv1_{t+1}
            in2T[(1024 + tid)*32 + b] = cv;    // for gemv2_t
        }
    } else if (bid < 42) {
        if (t == 0) return;
        int mc = bid - 32, t1 = t - 1;
        int m_l = tid & 7, b = (tid >> 3) & 31, kh = tid >> 8;
        int m = mc*8 + m_l;
        const float* cp = ctxp + (size_t)((t1 & 1)*32 + b)*512;
        float s = 0.f;
        for (int k = kh*384; k < kh*384 + 384; ++k) {
            float dv = (k < 1024) ? in2T[(1536+k)*32 + b] : cp[k - 1024];
            s = fmaf(dv, fw[k*80 + m], s);
        }
        s_red[tid] = s;
        __syncthreads();
        if (tid < 256) {
            float v4 = s_red[tid] + s_red[256+tid] + s_red[512+tid] + s_red[768+tid];
            int b2 = tid >> 3, m2 = mc*8 + (tid & 7);
            out[(b2*80 + m2)*400 + t1] = v4 + fb[m2];
        }
    } else {
        if (t == 0) return;
        int t1 = t - 1;
        int b = tid >> 5, kh = tid & 31;
        const float* cp = ctxp + (size_t)((t1 & 1)*32 + b)*512;
        float s = 0.f;
        for (int k = kh*48; k < kh*48 + 48; ++k) {
            float dv = (k < 1024) ? in2T[(1536+k)*32 + b] : cp[k - 1024];
            s = fmaf(dv, sw[k], s);
        }
        s_red[b*32 + kh] = s;
        __syncthreads();
        if (tid < 32) {
            float z = 0.f;
#pragma unroll
            for (int i = 0; i < 32; ++i) z += s_red[tid*32 + i];
            out[OUT_GATE + tid*400 + t1] = sigf(z + sb[0]);
        }
    }
}

// ---------------- K_C: gemv2(t) [128 blocks] ----------------
__global__ void __launch_bounds__(512) kernel_C(
    const float* __restrict__ l2k, const float* __restrict__ l2r, float* __restrict__ ws)
{
    __shared__ float s_acc[8192];
    float* zp2 = ws + OFF_ZP2;
    const float* in2T = ws + OFF_IN2T;
    const int tid = threadIdx.x, bid = blockIdx.x;
    const int colgrp = bid & 15, ksp = bid >> 4;
    const int jq = tid & 63, bgrp = (tid >> 6) & 3, ksub = tid >> 8;
    const int j = colgrp*256 + jq*4;
    const int b0 = bgrp*8;
    float4 a[8];
#pragma unroll
    for (int i = 0; i < 8; ++i) a[i] = make_float4(0.f, 0.f, 0.f, 0.f);
    const int k0 = ksp*320 + ksub*160;
    const int kend = k0 + 160;
    const int ka = min(kend, 1536);
#pragma unroll 2
    for (int k = k0; k < ka; ++k) {
        float4 w = *(const float4*)(l2k + (size_t)k*4096 + j);
        float4 xa = *(const float4*)(in2T + k*32 + b0);
        float4 xb = *(const float4*)(in2T + k*32 + b0 + 4);
        a[0].x = fmaf(xa.x, w.x, a[0].x); a[0].y = fmaf(xa.x, w.y, a[0].y); a[0].z = fmaf(xa.x, w.z, a[0].z); a[0].w = fmaf(xa.x, w.w, a[0].w);
        a[1].x = fmaf(xa.y, w.x, a[1].x); a[1].y = fmaf(xa.y, w.y, a[1].y); a[1].z = fmaf(xa.y, w.z, a[1].z); a[1].w = fmaf(xa.y, w.w, a[1].w);
        a[2].x = fmaf(xa.z, w.x, a[2].x); a[2].y = fmaf(xa.z, w.y, a[2].y); a[2].z = fmaf(xa.z, w.z, a[2].z); a[2].w = fmaf(xa.z, w.w, a[2].w);
        a[3].x = fmaf(xa.w, w.x, a[3].x); a[3].y = fmaf(xa.w, w.y, a[3].y); a[3].z = fmaf(xa.w, w.z, a[3].z); a[3].w = fmaf(xa.w, w.w, a[3].w);
        a[4].x = fmaf(xb.x, w.x, a[4].x); a[4].y = fmaf(xb.x, w.y, a[4].y); a[4].z = fmaf(xb.x, w.z, a[4].z); a[4].w = fmaf(xb.x, w.w, a[4].w);
        a[5].x = fmaf(xb.y, w.x, a[5].x); a[5].y = fmaf(xb.y, w.y, a[5].y); a[5].z = fmaf(xb.y, w.z, a[5].z); a[5].w = fmaf(xb.y, w.w, a[5].w);
        a[6].x = fmaf(xb.z, w.x, a[6].x); a[6].y = fmaf(xb.z, w.y, a[6].y); a[6].z = fmaf(xb.z, w.z, a[6].z); a[6].w = fmaf(xb.z, w.w, a[6].w);
        a[7].x = fmaf(xb.w, w.x, a[7].x); a[7].y = fmaf(xb.w, w.y, a[7].y); a[7].z = fmaf(xb.w, w.z, a[7].z); a[7].w = fmaf(xb.w, w.w, a[7].w);
    }
    const int kb = max(k0, 1536);
#pragma unroll 2
    for (int k = kb; k < kend; ++k) {
        float4 w = *(const float4*)(l2r + (size_t)(k - 1536)*4096 + j);
        float4 xa = *(const float4*)(in2T + k*32 + b0);
        float4 xb = *(const float4*)(in2T + k*32 + b0 + 4);
        a[0].x = fmaf(xa.x, w.x, a[0].x); a[0].y = fmaf(xa.x, w.y, a[0].y); a[0].z = fmaf(xa.x, w.z, a[0].z); a[0].w = fmaf(xa.x, w.w, a[0].w);
        a[1].x = fmaf(xa.y, w.x, a[1].x); a[1].y = fmaf(xa.y, w.y, a[1].y); a[1].z = fmaf(xa.y, w.z, a[1].z); a[1].w = fmaf(xa.y, w.w, a[1].w);
        a[2].x = fmaf(xa.z, w.x, a[2].x); a[2].y = fmaf(xa.z, w.y, a[2].y); a[2].z = fmaf(xa.z, w.z, a[2].z); a[2].w = fmaf(xa.z, w.w, a[2].w);
        a[3].x = fmaf(xa.w, w.x, a[3].x); a[3].y = fmaf(xa.w, w.y, a[3].y); a[3].z = fmaf(xa.w, w.z, a[3].z); a[3].w = fmaf(xa.w, w.w, a[3].w);
        a[4].x = fmaf(xb.x, w.x, a[4].x); a[4].y = fmaf(xb.x, w.y, a[4].y); a[4].z = fmaf(xb.x, w.z, a[4].z); a[4].w = fmaf(xb.x, w.w, a[4].w);
        a[5].x = fmaf(xb.y, w.x, a[5].x); a[5].y = fmaf(xb.y, w.y, a[5].y); a[5].z = fmaf(xb.y, w.z, a[5].z); a[5].w = fmaf(xb.y, w.w, a[5].w);
        a[6].x = fmaf(xb.z, w.x, a[6].x); a[6].y = fmaf(xb.z, w.y, a[6].y); a[6].z = fmaf(xb.z, w.z, a[6].z); a[6].w = fmaf(xb.z, w.w, a[6].w);
        a[7].x = fmaf(xb.w, w.x, a[7].x); a[7].y = fmaf(xb.w, w.y, a[7].y); a[7].z = fmaf(xb.w, w.z, a[7].z); a[7].w = fmaf(xb.w, w.w, a[7].w);
    }
    if (ksub == 1) {
#pragma unroll
        for (int i = 0; i < 8; ++i)
            *(float4*)(s_acc + (b0 + i)*256 + jq*4) = a[i];
    }
    __syncthreads();
    if (ksub == 0) {
#pragma unroll
        for (int i = 0; i < 8; ++i) {
            float4 r = *(const float4*)(s_acc + (b0 + i)*256 + jq*4);
            a[i].x += r.x; a[i].y += r.y; a[i].z += r.z; a[i].w += r.w;
            *(float4*)(zp2 + (size_t)(ksp*32 + b0 + i)*4096 + j) = a[i];
        }
    }
}

extern "C" void kernel_launch(void* const* d_in, const int* in_sizes, int n_in,
                              void* d_out, int out_size, void* d_ws, size_t ws_size,
                              hipStream_t stream) {
    (void)in_sizes; (void)n_in; (void)out_size;
    const float* mp    = (const float*)d_in[0];
    const float* dec   = (const float*)d_in[1];
    const float* pw0   = (const float*)d_in[2];
    const float* pb0   = (const float*)d_in[3];
    const float* pw1   = (const float*)d_in[4];
    const float* pb1   = (const float*)d_in[5];
    const float* l1k   = (const float*)d_in[6];
    const float* l1r   = (const float*)d_in[7];
    const float* l1b   = (const float*)d_in[8];
    const float* l2k   = (const float*)d_in[9];
    const float* l2r   = (const float*)d_in[10];
    const float* l2b   = (const float*)d_in[11];
    const float* wq    = (const float*)d_in[12];
    const float* wm    = (const float*)d_in[13];
    const float* vvec  = (const float*)d_in[14];
    const float* lconv = (const float*)d_in[15];
    const float* ldns  = (const float*)d_in[16];
    const float* fw    = (const float*)d_in[17];
    const float* fb    = (const float*)d_in[18];
    const float* sw    = (const float*)d_in[19];
    const float* sb    = (const float*)d_in[20];
    float* ws  = (float*)d_ws;
    float* out = (float*)d_out;

    if (ws_size < (size_t)WS_FLOATS * sizeof(float)) return;

    prenet_kernel<<<dim3(400, 32), 256, 0, stream>>>(dec, pw0, pb0, pw1, pb1, ws);
    pmem_kernel  <<<dim3(200, 32), 128, 0, stream>>>(mp, wm, ws);
    zero_kernel  <<<256, 256, 0, stream>>>(ws);

    for (int t = 0; t < TSTEPS; ++t) {
        kernel_A<<<144, 512, 0, stream>>>(l1k, l1r, l2b, ws, t);
        kernel_B<<<43, 1024, 0, stream>>>(mp, l1b, wq, vvec, lconv, ldns, fw, fb, sw, sb, ws, out, t);
        kernel_C<<<128, 512, 0, stream>>>(l2k, l2r, ws);
    }
    // tail: gates2 + mel/stop for t = 399
    kernel_A<<<144, 512, 0, stream>>>(l1k, l1r, l2b, ws, TSTEPS);
    kernel_B<<<43, 1024, 0, stream>>>(mp, l1b, wq, vvec, lconv, ldns, fw, fb, sw, sb, ws, out, TSTEPS);
}